// Round 2
// baseline (196.898 us; speedup 1.0000x reference)
//
#include <hip/hip_runtime.h>
#include <hip/hip_bf16.h>
#include <stdint.h>

#define B_ 64
#define S_ 512
#define I_ 256
#define H_ 1024
#define O_ 128
#define M_ (B_*S_)   // 32768

typedef float f32x4 __attribute__((ext_vector_type(4)));

// ---- K0: fp32 -> fp8 e4m3 into per-lane fragment order, via LDS transpose.
// A region: [tile128][kq(8)][rb(8)][lane*8B]  (tile = 128 t-rows, 32 KB)
// B region: [hn16(16)][kq(8)][rb(4)][lane*8B] (tile = 64 h-rows, 16 KB)
// Fragment semantics: lane l holds row rb*16+(l&15), k = kq*32+(l>>4)*8..+8.
__global__ void __launch_bounds__(256) k0_convert(
    const float* __restrict__ x, const float* __restrict__ Win,
    uint8_t* __restrict__ xf8, uint8_t* __restrict__ wf8,
    unsigned* __restrict__ firstCross, unsigned* __restrict__ doneCnt)
{
    __shared__ unsigned lds32[64 * 65];   // 16.6 KB
    const int i = blockIdx.x;             // 0..511 x-blocks, 512..527 W-blocks
    const int t = threadIdx.x;

    const float* src;
    uint8_t* dstBase;
    int kqStride;
    if (i < 512) {
        const int r0 = i * 64;                  // global x row
        src = x + (size_t)r0 * 256;
        const int T = i >> 1;                   // 128-row tile
        const int rbase = (i & 1) * 4;          // rb offset (0 or 4)
        dstBase = xf8 + (size_t)T * 32768 + rbase * 512;
        kqStride = 4096;
    } else {
        const int i2 = i - 512;
        src = Win + (size_t)(i2 * 64) * 256;
        dstBase = wf8 + (size_t)i2 * 16384;
        kqStride = 2048;
    }

    // read phase: 64 rows x 256 floats, wave reads one full 1KB row per inst
#pragma unroll
    for (int j = 0; j < 16; ++j) {
        const int f = j * 256 + t;          // float4 index
        const int lrow = f >> 6, c4 = f & 63;
        float4 v = *(const float4*)(src + (size_t)lrow * 256 + c4 * 4);
        int w0 = 0;
        w0 = __builtin_amdgcn_cvt_pk_fp8_f32(v.x, v.y, w0, false);
        w0 = __builtin_amdgcn_cvt_pk_fp8_f32(v.z, v.w, w0, true);
        lds32[lrow * 65 + c4] = (unsigned)w0;
    }
    __syncthreads();

    // write phase: 1024 x 16B chunks in fragment order, contiguous per wave
#pragma unroll
    for (int j = 0; j < 4; ++j) {
        const int c = j * 256 + t;          // 16B chunk index
        const int kq  = c >> 7;
        const int rem = c & 127;
        const int rbl = rem >> 5;           // 0..3 local 16-row group
        const int l0  = (rem & 31) * 2;     // even lane
        const int r   = l0 & 15;
        const int q   = l0 >> 4;            // k-chunk 0..3
        const int lrow = rbl * 16 + r;
        const int c0 = kq * 8 + q * 2;
        uint4 o;
        o.x = lds32[lrow * 65 + c0];
        o.y = lds32[lrow * 65 + c0 + 1];
        o.z = lds32[(lrow + 1) * 65 + c0];
        o.w = lds32[(lrow + 1) * 65 + c0 + 1];
        *(uint4*)(dstBase + kq * kqStride + rbl * 512 + l0 * 8) = o;
    }

    if (i == 0 && t < 128) {
        if (t < 64) firstCross[t] = 0xFFFFFFFFu;
        else        doneCnt[t - 64] = 0u;
    }
}

// ---- KF: fp8 GEMM + max-tracking scan + fused fast-path output ------------
// 1024 blocks = (b 64) x (hn 16 tiles of 64 h). 4 blocks/CU, 16 waves/CU.
// Wave w owns t-band w*32..+31 (acc 2x4). B frags register-resident.
// Scan only tracks max(mem) — firstCross is consumed as a boolean by k3 and
// the epilogue, so per-step timestamp bookkeeping is dead code.
// Last-arriver (doneCnt ticket) per b writes the sigmoid(b_out) fast-path
// output slice; any race vs a crossing batch is safe because k3 (stream-
// ordered later) fully overwrites out[b] for crossed batches.
__global__ void __launch_bounds__(256, 4) kf_gemm_scan(
    const uint8_t* __restrict__ xf8, const uint8_t* __restrict__ wf8,
    const float* __restrict__ b_in, const float* __restrict__ b_rec,
    const float* __restrict__ tau_m, const float* __restrict__ tau_n,
    const float* __restrict__ b_out,
    unsigned* __restrict__ firstCross, unsigned* __restrict__ doneCnt,
    float* __restrict__ out)
{
    __shared__ float lsf[128 * 65];    // 33.3 KB, [t(128)][h(64)] stride 65

    const int tid  = threadIdx.x;
    const int w    = tid >> 6;
    const int lane = tid & 63;
    const int idx  = blockIdx.x;
    const int b    = (idx & 7) | ((idx >> 7) << 3);   // XCD swizzle
    const int hn   = (idx >> 3) & 15;
    const int colrow = lane & 15;
    const int quad   = lane >> 4;

    // scan state: threads 0..63 own one h column each
    float alpha = 0.f, beta = 0.f, cbr = 0.f, oma = 0.f, ombr = 0.f;
    float d = 0.f, mem = 0.f, mx = -1.0f;
    if (tid < 64) {
        const int hs = hn * 64 + tid;
        alpha = 1.f / (1.f + expf(-tau_m[hs]));
        beta  = 1.f / (1.f + expf(-tau_n[hs]));
        oma = 1.f - alpha; ombr = 1.f - beta;
        cbr = ombr * (b_in[hs] + b_rec[hs]);
    }

    // B fragments, resident across all 4 t-tiles: 32 x 8B
    const uint8_t* wB = wf8 + (size_t)hn * 16384 + lane * 8;
    long long bq[32];
#pragma unroll
    for (int kq = 0; kq < 8; ++kq)
#pragma unroll
        for (int ni = 0; ni < 4; ++ni)
            bq[kq * 4 + ni] = *(const long long*)(wB + kq * 2048 + ni * 512);

    for (int tt = 0; tt < 4; ++tt) {
        const uint8_t* xA = xf8 + (size_t)(b * 4 + tt) * 32768
                          + w * 1024 + lane * 8;   // rb base = w*2

        f32x4 acc[2][4];
#pragma unroll
        for (int mi = 0; mi < 2; ++mi)
#pragma unroll
            for (int ni = 0; ni < 4; ++ni)
                acc[mi][ni] = (f32x4){0.f, 0.f, 0.f, 0.f};

#pragma unroll
        for (int kq = 0; kq < 8; ++kq) {
            long long a[2];
#pragma unroll
            for (int mi = 0; mi < 2; ++mi)
                a[mi] = *(const long long*)(xA + kq * 4096 + mi * 512);
#pragma unroll
            for (int mi = 0; mi < 2; ++mi)
#pragma unroll
                for (int ni = 0; ni < 4; ++ni)
                    acc[mi][ni] = __builtin_amdgcn_mfma_f32_16x16x32_fp8_fp8(
                        a[mi], bq[kq * 4 + ni], acc[mi][ni], 0, 0, 0);
        }

        __syncthreads();   // prior tile's scan readers done with lsf

        // dump: wave w covers t = w*32 + mi*16 + quad*4 + r, h = ni*16+colrow
#pragma unroll
        for (int mi = 0; mi < 2; ++mi) {
            const int t0 = w * 32 + mi * 16 + quad * 4;
#pragma unroll
            for (int ni = 0; ni < 4; ++ni) {
                const int h0 = ni * 16 + colrow;
                float* p = lsf + t0 * 65 + h0;
                p[0]      = acc[mi][ni][0];
                p[65]     = acc[mi][ni][1];
                p[130]    = acc[mi][ni][2];
                p[195]    = acc[mi][ni][3];
            }
        }
        __syncthreads();

        if (tid < 64) {
            for (int tl0 = 0; tl0 < 128; tl0 += 16) {
                float f[16];
#pragma unroll
                for (int u = 0; u < 16; ++u)
                    f[u] = lsf[(tl0 + u) * 65 + tid];
#pragma unroll
                for (int u = 0; u < 16; ++u) {
                    d   = fmaf(beta,  d,   fmaf(ombr, f[u], cbr));
                    mem = fmaf(alpha, mem, oma * d);
                    mx  = fmaxf(mx, mem);
                }
            }
        }
    }

    if (tid < 64 && mx > 1.0f) atomicMin(firstCross + b, 0u);
    __threadfence();
    __syncthreads();

    // last-arriver ticket: the 16th block for this b owns the fast-path out
    __shared__ unsigned sLast, sFc;
    if (tid == 0) {
        unsigned old = atomicAdd(doneCnt + b, 1u);
        sLast = (old == 15u) ? 1u : 0u;
        sFc   = (old == 15u) ? atomicMin(firstCross + b, 0xFFFFFFFFu) : 0u;
    }
    __syncthreads();
    if (sLast && sFc == 0xFFFFFFFFu) {
        // out[b] slice: 16384 float4; thread's o-column constant across iters
        float4 v = *(const float4*)(b_out + (tid & 31) * 4);
        float4 r;
        r.x = 1.f / (1.f + expf(-v.x));
        r.y = 1.f / (1.f + expf(-v.y));
        r.z = 1.f / (1.f + expf(-v.z));
        r.w = 1.f / (1.f + expf(-v.w));
        float4* dst = (float4*)(out + (size_t)b * S_ * O_);
#pragma unroll 4
        for (int it = 0; it < 64; ++it)
            dst[it * 256 + tid] = r;
    }
}

// ---- K3: exact repair + output for spiking batches (runs ~never) ----------
__global__ void __launch_bounds__(1024) k3_repair(
    const float* __restrict__ x, const float* __restrict__ W_in,
    const float* __restrict__ b_in,
    const float* __restrict__ W_rec, const float* __restrict__ b_rec,
    const float* __restrict__ tau_m, const float* __restrict__ tau_n,
    const float* __restrict__ W_out, const float* __restrict__ b_out,
    const unsigned* __restrict__ firstCross,
    unsigned long long* __restrict__ gmask,
    float* __restrict__ out)
{
    const int b = blockIdx.x;
    if (firstCross[b] == 0xFFFFFFFFu) return;   // block-uniform
    const int h = threadIdx.x;
    __shared__ float xrow[I_];
    __shared__ unsigned long long msk[16];
    if (h < 16) msk[h] = 0ull;
    const float alpha = 1.f / (1.f + expf(-tau_m[h]));
    const float beta  = 1.f / (1.f + expf(-tau_n[h]));
    const float bsum  = b_in[h] + b_rec[h];
    const float* wi = W_in + (size_t)h * I_;
    const float* wr = W_rec + (size_t)h * H_;
    float d = 0.f, mem = 0.f;
    for (int t = 0; t < S_; ++t) {
        __syncthreads();
        if (h < I_) xrow[h] = x[((size_t)b * S_ + t) * I_ + h];
        __syncthreads();
        float ffv = 0.f;
        for (int k = 0; k < I_; ++k) ffv += xrow[k] * wi[k];
        float rec = 0.f;
#pragma unroll
        for (int wd = 0; wd < 16; ++wd) {
            unsigned long long mw = msk[wd];
            while (mw) {
                int bit = __ffsll((long long)mw) - 1;
                rec += wr[(wd << 6) + bit];
                mw &= (mw - 1);
            }
        }
        float tot = ffv + bsum + rec;
        d   = beta  * d   + (1.f - beta)  * tot;
        mem = alpha * mem + (1.f - alpha) * d;
        int sp = (mem > 1.0f) ? 1 : 0;
        if (sp) mem = 0.f;
        unsigned long long bal = __ballot(sp);
        __syncthreads();
        if ((h & 63) == 0) {
            msk[h >> 6] = bal;
            gmask[((size_t)b * S_ + t) * 16 + (h >> 6)] = bal;
        }
    }
    __syncthreads();
    __threadfence_block();
    // phase 2: outputs for this whole batch (rare path)
    for (int i = h; i < S_ * O_; i += 1024) {
        const int t = i >> 7, o = i & (O_ - 1);
        float logit = b_out[o];
        const unsigned long long* m = gmask + ((size_t)b * S_ + t) * 16;
        const float* wo = W_out + (size_t)o * H_;
        for (int wd = 0; wd < 16; ++wd) {
            unsigned long long mw = m[wd];
            while (mw) {
                int bit = __ffsll((long long)mw) - 1;
                logit += wo[(wd << 6) + bit];
                mw &= (mw - 1);
            }
        }
        out[((size_t)b * S_ + t) * O_ + o] = 1.f / (1.f + expf(-logit));
    }
}

extern "C" void kernel_launch(void* const* d_in, const int* in_sizes, int n_in,
                              void* d_out, int out_size, void* d_ws, size_t ws_size,
                              hipStream_t stream) {
    const float* x     = (const float*)d_in[0];
    const float* W_in  = (const float*)d_in[1];
    const float* b_in  = (const float*)d_in[2];
    const float* W_rec = (const float*)d_in[3];
    const float* b_rec = (const float*)d_in[4];
    const float* tau_m = (const float*)d_in[5];
    const float* tau_n = (const float*)d_in[6];
    const float* W_out = (const float*)d_in[7];
    const float* b_out = (const float*)d_in[8];
    float* out = (float*)d_out;

    char* ws = (char*)d_ws;
    size_t off = 0;
    uint8_t* xf8 = (uint8_t*)(ws + off);               off += (size_t)M_ * I_;        // 8 MB
    uint8_t* wf8 = (uint8_t*)(ws + off);               off += (size_t)H_ * I_;        // 256 KB
    unsigned long long* gmask = (unsigned long long*)(ws + off); off += (size_t)B_ * S_ * 16 * 8; // 4 MB
    unsigned* firstCross = (unsigned*)(ws + off);      off += 256;
    unsigned* doneCnt = (unsigned*)(ws + off);         off += 256;
    if (ws_size < off) return;

    k0_convert<<<528, 256, 0, stream>>>(x, W_in, xf8, wf8, firstCross, doneCnt);
    kf_gemm_scan<<<1024, 256, 0, stream>>>(xf8, wf8, b_in, b_rec, tau_m, tau_n,
                                           b_out, firstCross, doneCnt, out);
    k3_repair<<<64, 1024, 0, stream>>>(x, W_in, b_in, W_rec, b_rec, tau_m, tau_n,
                                       W_out, b_out, firstCross, gmask, out);
}

// Round 3
// 119.821 us; speedup vs baseline: 1.6433x; 1.6433x over previous
//
#include <hip/hip_runtime.h>
#include <hip/hip_bf16.h>
#include <stdint.h>

#define B_ 64
#define S_ 512
#define I_ 256
#define H_ 1024
#define O_ 128
#define M_ (B_*S_)   // 32768

typedef float f32x4 __attribute__((ext_vector_type(4)));

// ---- K0: fp32 -> fp8 e4m3 into per-lane fragment order, via LDS transpose.
// A region: [tile128][kq(8)][rb(8)][lane*8B]  (tile = 128 t-rows, 32 KB)
// B region: [hn16(16)][kq(8)][rb(4)][lane*8B] (tile = 64 h-rows, 16 KB)
// Fragment semantics: lane l holds row rb*16+(l&15), k = kq*32+(l>>4)*8..+8.
__global__ void __launch_bounds__(256) k0_convert(
    const float* __restrict__ x, const float* __restrict__ Win,
    uint8_t* __restrict__ xf8, uint8_t* __restrict__ wf8,
    unsigned* __restrict__ firstCross)
{
    __shared__ unsigned lds32[64 * 65];   // 16.6 KB
    const int i = blockIdx.x;             // 0..511 x-blocks, 512..527 W-blocks
    const int t = threadIdx.x;

    const float* src;
    uint8_t* dstBase;
    int kqStride;
    if (i < 512) {
        const int r0 = i * 64;                  // global x row
        src = x + (size_t)r0 * 256;
        const int T = i >> 1;                   // 128-row tile
        const int rbase = (i & 1) * 4;          // rb offset (0 or 4)
        dstBase = xf8 + (size_t)T * 32768 + rbase * 512;
        kqStride = 4096;
    } else {
        const int i2 = i - 512;
        src = Win + (size_t)(i2 * 64) * 256;
        dstBase = wf8 + (size_t)i2 * 16384;
        kqStride = 2048;
    }

    // read phase: 64 rows x 256 floats, wave reads one full 1KB row per inst
#pragma unroll
    for (int j = 0; j < 16; ++j) {
        const int f = j * 256 + t;          // float4 index
        const int lrow = f >> 6, c4 = f & 63;
        float4 v = *(const float4*)(src + (size_t)lrow * 256 + c4 * 4);
        int w0 = 0;
        w0 = __builtin_amdgcn_cvt_pk_fp8_f32(v.x, v.y, w0, false);
        w0 = __builtin_amdgcn_cvt_pk_fp8_f32(v.z, v.w, w0, true);
        lds32[lrow * 65 + c4] = (unsigned)w0;
    }
    __syncthreads();

    // write phase: 1024 x 16B chunks in fragment order, contiguous per wave
#pragma unroll
    for (int j = 0; j < 4; ++j) {
        const int c = j * 256 + t;          // 16B chunk index
        const int kq  = c >> 7;
        const int rem = c & 127;
        const int rbl = rem >> 5;           // 0..3 local 16-row group
        const int l0  = (rem & 31) * 2;     // even lane
        const int r   = l0 & 15;
        const int q   = l0 >> 4;            // k-chunk 0..3
        const int lrow = rbl * 16 + r;
        const int c0 = kq * 8 + q * 2;
        uint4 o;
        o.x = lds32[lrow * 65 + c0];
        o.y = lds32[lrow * 65 + c0 + 1];
        o.z = lds32[(lrow + 1) * 65 + c0];
        o.w = lds32[(lrow + 1) * 65 + c0 + 1];
        *(uint4*)(dstBase + kq * kqStride + rbl * 512 + l0 * 8) = o;
    }

    if (i == 0 && t < 64) firstCross[t] = 0xFFFFFFFFu;
}

// ---- KF: fp8 GEMM + max-tracking scan + distributed fast-path output ------
// 1024 blocks = (b 64) x (hn 16 tiles of 64 h). 4 blocks/CU, 16 waves/CU.
// Wave w owns t-band w*32..+31 (acc 2x4). B frags register-resident.
// Scan tracks max(mem) only (firstCross consumed as boolean).
// NO cross-block sync: each (b,hn) block unconditionally writes its own
// 32-t-row slice of out[b] with sigmoid(b_out) (input-only dependency);
// k3 (stream-ordered later) fully overwrites crossed batches. This replaces
// the R2 ticket+__threadfence design whose per-block device fences blew L2
// (FETCH 22MB vs 9MB ideal, kf 98us) — lesson: device-scope fences inside a
// hot kernel invalidate caches for all concurrent blocks on the XCD.
__global__ void __launch_bounds__(256, 4) kf_gemm_scan(
    const uint8_t* __restrict__ xf8, const uint8_t* __restrict__ wf8,
    const float* __restrict__ b_in, const float* __restrict__ b_rec,
    const float* __restrict__ tau_m, const float* __restrict__ tau_n,
    const float* __restrict__ b_out,
    unsigned* __restrict__ firstCross,
    float* __restrict__ out)
{
    // [t(128)][h(64)] stride 68: dump banks = colrow + 16*(quad&1) -> exactly
    // 2 lanes/bank (free, m136); stride 65 was 4-way. Scan reads bank=tid%32.
    __shared__ float lsf[128 * 68];    // 34.8 KB, 4 blocks/CU

    const int tid  = threadIdx.x;
    const int w    = tid >> 6;
    const int lane = tid & 63;
    const int idx  = blockIdx.x;
    const int b    = (idx & 7) | ((idx >> 7) << 3);   // XCD swizzle
    const int hn   = (idx >> 3) & 15;
    const int colrow = lane & 15;
    const int quad   = lane >> 4;

    // scan state: threads 0..63 own one h column each
    float alpha = 0.f, beta = 0.f, cbr = 0.f, oma = 0.f, ombr = 0.f;
    float d = 0.f, mem = 0.f, mx = -1.0f;
    if (tid < 64) {
        const int hs = hn * 64 + tid;
        alpha = 1.f / (1.f + expf(-tau_m[hs]));
        beta  = 1.f / (1.f + expf(-tau_n[hs]));
        oma = 1.f - alpha; ombr = 1.f - beta;
        cbr = ombr * (b_in[hs] + b_rec[hs]);
    }

    // B fragments, resident across all 4 t-tiles: 32 x 8B
    const uint8_t* wB = wf8 + (size_t)hn * 16384 + lane * 8;
    long long bq[32];
#pragma unroll
    for (int kq = 0; kq < 8; ++kq)
#pragma unroll
        for (int ni = 0; ni < 4; ++ni)
            bq[kq * 4 + ni] = *(const long long*)(wB + kq * 2048 + ni * 512);

    for (int tt = 0; tt < 4; ++tt) {
        const uint8_t* xA = xf8 + (size_t)(b * 4 + tt) * 32768
                          + w * 1024 + lane * 8;   // rb base = w*2

        f32x4 acc[2][4];
#pragma unroll
        for (int mi = 0; mi < 2; ++mi)
#pragma unroll
            for (int ni = 0; ni < 4; ++ni)
                acc[mi][ni] = (f32x4){0.f, 0.f, 0.f, 0.f};

#pragma unroll
        for (int kq = 0; kq < 8; ++kq) {
            long long a[2];
#pragma unroll
            for (int mi = 0; mi < 2; ++mi)
                a[mi] = *(const long long*)(xA + kq * 4096 + mi * 512);
#pragma unroll
            for (int mi = 0; mi < 2; ++mi)
#pragma unroll
                for (int ni = 0; ni < 4; ++ni)
                    acc[mi][ni] = __builtin_amdgcn_mfma_f32_16x16x32_fp8_fp8(
                        a[mi], bq[kq * 4 + ni], acc[mi][ni], 0, 0, 0);
        }

        __syncthreads();   // prior tile's scan readers done with lsf

        // dump: wave w covers t = w*32 + mi*16 + quad*4 + r, h = ni*16+colrow
#pragma unroll
        for (int mi = 0; mi < 2; ++mi) {
            const int t0 = w * 32 + mi * 16 + quad * 4;
#pragma unroll
            for (int ni = 0; ni < 4; ++ni) {
                const int h0 = ni * 16 + colrow;
                float* p = lsf + t0 * 68 + h0;
                p[0]        = acc[mi][ni][0];
                p[68]       = acc[mi][ni][1];
                p[136]      = acc[mi][ni][2];
                p[204]      = acc[mi][ni][3];
            }
        }
        __syncthreads();

        if (tid < 64) {
            for (int tl0 = 0; tl0 < 128; tl0 += 16) {
                float f[16];
#pragma unroll
                for (int u = 0; u < 16; ++u)
                    f[u] = lsf[(tl0 + u) * 68 + tid];
#pragma unroll
                for (int u = 0; u < 16; ++u) {
                    d   = fmaf(beta,  d,   fmaf(ombr, f[u], cbr));
                    mem = fmaf(alpha, mem, oma * d);
                    mx  = fmaxf(mx, mem);
                }
            }
        }
    }

    if (tid < 64 && mx > 1.0f) atomicMin(firstCross + b, 0u);

    // distributed fast-path out: this block writes out[b, hn*32 .. hn*32+31, :]
    // = 1024 float4, 4 per thread. Value depends only on b_out (input), so no
    // inter-block ordering is needed; k3 overwrites crossed batches later.
    float4 v = *(const float4*)(b_out + (tid & 31) * 4);
    float4 r;
    r.x = 1.f / (1.f + expf(-v.x));
    r.y = 1.f / (1.f + expf(-v.y));
    r.z = 1.f / (1.f + expf(-v.z));
    r.w = 1.f / (1.f + expf(-v.w));
    float4* dst = (float4*)(out + ((size_t)b * S_ + (size_t)hn * 32) * O_);
#pragma unroll
    for (int it = 0; it < 4; ++it)
        dst[it * 256 + tid] = r;
}

// ---- K3: exact repair + output for spiking batches (runs ~never) ----------
__global__ void __launch_bounds__(1024) k3_repair(
    const float* __restrict__ x, const float* __restrict__ W_in,
    const float* __restrict__ b_in,
    const float* __restrict__ W_rec, const float* __restrict__ b_rec,
    const float* __restrict__ tau_m, const float* __restrict__ tau_n,
    const float* __restrict__ W_out, const float* __restrict__ b_out,
    const unsigned* __restrict__ firstCross,
    unsigned long long* __restrict__ gmask,
    float* __restrict__ out)
{
    const int b = blockIdx.x;
    if (firstCross[b] == 0xFFFFFFFFu) return;   // block-uniform
    const int h = threadIdx.x;
    __shared__ float xrow[I_];
    __shared__ unsigned long long msk[16];
    if (h < 16) msk[h] = 0ull;
    const float alpha = 1.f / (1.f + expf(-tau_m[h]));
    const float beta  = 1.f / (1.f + expf(-tau_n[h]));
    const float bsum  = b_in[h] + b_rec[h];
    const float* wi = W_in + (size_t)h * I_;
    const float* wr = W_rec + (size_t)h * H_;
    float d = 0.f, mem = 0.f;
    for (int t = 0; t < S_; ++t) {
        __syncthreads();
        if (h < I_) xrow[h] = x[((size_t)b * S_ + t) * I_ + h];
        __syncthreads();
        float ffv = 0.f;
        for (int k = 0; k < I_; ++k) ffv += xrow[k] * wi[k];
        float rec = 0.f;
#pragma unroll
        for (int wd = 0; wd < 16; ++wd) {
            unsigned long long mw = msk[wd];
            while (mw) {
                int bit = __ffsll((long long)mw) - 1;
                rec += wr[(wd << 6) + bit];
                mw &= (mw - 1);
            }
        }
        float tot = ffv + bsum + rec;
        d   = beta  * d   + (1.f - beta)  * tot;
        mem = alpha * mem + (1.f - alpha) * d;
        int sp = (mem > 1.0f) ? 1 : 0;
        if (sp) mem = 0.f;
        unsigned long long bal = __ballot(sp);
        __syncthreads();
        if ((h & 63) == 0) {
            msk[h >> 6] = bal;
            gmask[((size_t)b * S_ + t) * 16 + (h >> 6)] = bal;
        }
    }
    __syncthreads();
    __threadfence_block();
    // phase 2: outputs for this whole batch (rare path)
    for (int i = h; i < S_ * O_; i += 1024) {
        const int t = i >> 7, o = i & (O_ - 1);
        float logit = b_out[o];
        const unsigned long long* m = gmask + ((size_t)b * S_ + t) * 16;
        const float* wo = W_out + (size_t)o * H_;
        for (int wd = 0; wd < 16; ++wd) {
            unsigned long long mw = m[wd];
            while (mw) {
                int bit = __ffsll((long long)mw) - 1;
                logit += wo[(wd << 6) + bit];
                mw &= (mw - 1);
            }
        }
        out[((size_t)b * S_ + t) * O_ + o] = 1.f / (1.f + expf(-logit));
    }
}

extern "C" void kernel_launch(void* const* d_in, const int* in_sizes, int n_in,
                              void* d_out, int out_size, void* d_ws, size_t ws_size,
                              hipStream_t stream) {
    const float* x     = (const float*)d_in[0];
    const float* W_in  = (const float*)d_in[1];
    const float* b_in  = (const float*)d_in[2];
    const float* W_rec = (const float*)d_in[3];
    const float* b_rec = (const float*)d_in[4];
    const float* tau_m = (const float*)d_in[5];
    const float* tau_n = (const float*)d_in[6];
    const float* W_out = (const float*)d_in[7];
    const float* b_out = (const float*)d_in[8];
    float* out = (float*)d_out;

    char* ws = (char*)d_ws;
    size_t off = 0;
    uint8_t* xf8 = (uint8_t*)(ws + off);               off += (size_t)M_ * I_;        // 8 MB
    uint8_t* wf8 = (uint8_t*)(ws + off);               off += (size_t)H_ * I_;        // 256 KB
    unsigned long long* gmask = (unsigned long long*)(ws + off); off += (size_t)B_ * S_ * 16 * 8; // 4 MB
    unsigned* firstCross = (unsigned*)(ws + off);      off += 256;
    if (ws_size < off) return;

    k0_convert<<<528, 256, 0, stream>>>(x, W_in, xf8, wf8, firstCross);
    kf_gemm_scan<<<1024, 256, 0, stream>>>(xf8, wf8, b_in, b_rec, tau_m, tau_n,
                                           b_out, firstCross, out);
    k3_repair<<<64, 1024, 0, stream>>>(x, W_in, b_in, W_rec, b_rec, tau_m, tau_n,
                                       W_out, b_out, firstCross, gmask, out);
}